// Round 1
// baseline (3925.823 us; speedup 1.0000x reference)
//
#include <hip/hip_runtime.h>

#define NB 4
#define P 1024
#define ITERS 50
#define WPB 64            // workgroups per batch
#define THREADS 256
#define K_COEF (-14.426950408889634f)  // -log2(e)/eps, eps=0.1
#define DELTA 1e-8f

// ws layout: [0,16KB) a_g[NB][P] f32 | [16KB,32KB) b_g[NB][P] f32 | [32KB,+1600B) cnt[NB*2*ITERS] int

__global__ void sink_zero(int* cnt, float* out) {
    int t = threadIdx.x;
    if (t < NB * 2 * ITERS) cnt[t] = 0;
    if (t < NB) out[t] = 0.0f;
}

__device__ __forceinline__ void batch_barrier(int* c) {
    __syncthreads();  // drains vmcnt: all release-stores of this WG complete
    if (threadIdx.x == 0) {
        __hip_atomic_fetch_add(c, 1, __ATOMIC_RELEASE, __HIP_MEMORY_SCOPE_AGENT);
        while (__hip_atomic_load(c, __ATOMIC_RELAXED, __HIP_MEMORY_SCOPE_AGENT) < WPB) {
            __builtin_amdgcn_s_sleep(1);
        }
        (void)__hip_atomic_load(c, __ATOMIC_ACQUIRE, __HIP_MEMORY_SCOPE_AGENT);
    }
    __syncthreads();
}

__global__ __launch_bounds__(THREADS, 1)
void sink_main(const float* __restrict__ mu, const float* __restrict__ nu,
               const float* __restrict__ C, float* __restrict__ out,
               float* __restrict__ wsf, int* __restrict__ cnt) {
    const int n   = blockIdx.x >> 6;   // batch
    const int w   = blockIdx.x & 63;   // wg within batch
    const int tid = threadIdx.x;
    const int wq  = tid >> 6;          // wave id 0..3
    const int l   = tid & 63;          // lane

    float* a_g = wsf + n * P;
    float* b_g = wsf + NB * P + n * P;
    int*   cb  = cnt + n * (2 * ITERS);

    const float* Cb = C + (size_t)n * P * P;
    const int base_rc = w * 16 + 4 * wq;   // first of this wave's 4 rows (and cols)

    float Kr[4][16], Kt[4][16], muv[4], nuv[4];

    // ---- load K rows (coalesced float4) : Kr[q][k] = K[base_rc+q][16*l+k]
    #pragma unroll
    for (int q = 0; q < 4; ++q) {
        const int r = base_rc + q;
        const float4* src = reinterpret_cast<const float4*>(Cb + (size_t)r * P + 16 * l);
        #pragma unroll
        for (int m = 0; m < 4; ++m) {
            float4 c4 = src[m];
            Kr[q][4*m+0] = exp2f(K_COEF * c4.x);
            Kr[q][4*m+1] = exp2f(K_COEF * c4.y);
            Kr[q][4*m+2] = exp2f(K_COEF * c4.z);
            Kr[q][4*m+3] = exp2f(K_COEF * c4.w);
        }
        muv[q] = mu[n * P + r] + DELTA;
        nuv[q] = nu[n * P + r] + DELTA;   // cols share the same index range
    }
    // ---- load K columns (one-time, strided) : Kt[q][k] = K[16*l+k][base_rc+q]
    #pragma unroll
    for (int q = 0; q < 4; ++q) {
        const int c = base_rc + q;
        #pragma unroll
        for (int k = 0; k < 16; ++k)
            Kt[q][k] = exp2f(K_COEF * Cb[(size_t)(16 * l + k) * P + c]);
    }

    float b_r[16];
    #pragma unroll
    for (int k = 0; k < 16; ++k) b_r[k] = 1.0f;   // v=0 -> b=1
    float a_own[4];

    for (int t = 0; t < ITERS; ++t) {
        if (t) {
            const float4* bs = reinterpret_cast<const float4*>(b_g + 16 * l);
            #pragma unroll
            for (int m = 0; m < 4; ++m) {
                float4 v4 = bs[m];
                b_r[4*m+0] = v4.x; b_r[4*m+1] = v4.y;
                b_r[4*m+2] = v4.z; b_r[4*m+3] = v4.w;
            }
        }
        // phase A: a_i = (mu_i+d) / sum_j K_ij b_j  (wave-per-row, lane covers j=16l+k)
        #pragma unroll
        for (int q = 0; q < 4; ++q) {
            float y = 0.f;
            #pragma unroll
            for (int k = 0; k < 16; ++k) y += Kr[q][k] * b_r[k];
            #pragma unroll
            for (int off = 32; off > 0; off >>= 1) y += __shfl_xor(y, off, 64);
            a_own[q] = muv[q] / y;
            if (l == 0)
                __hip_atomic_store(&a_g[base_rc + q], a_own[q],
                                   __ATOMIC_RELEASE, __HIP_MEMORY_SCOPE_AGENT);
        }
        batch_barrier(cb + 2 * t);
        // phase B: b_j = (nu_j+d) / sum_i K_ij a_i  (wave-per-col via Kt)
        {
            float a_r[16];
            const float4* as = reinterpret_cast<const float4*>(a_g + 16 * l);
            #pragma unroll
            for (int m = 0; m < 4; ++m) {
                float4 v4 = as[m];
                a_r[4*m+0] = v4.x; a_r[4*m+1] = v4.y;
                a_r[4*m+2] = v4.z; a_r[4*m+3] = v4.w;
            }
            #pragma unroll
            for (int q = 0; q < 4; ++q) {
                float y = 0.f;
                #pragma unroll
                for (int k = 0; k < 16; ++k) y += Kt[q][k] * a_r[k];
                #pragma unroll
                for (int off = 32; off > 0; off >>= 1) y += __shfl_xor(y, off, 64);
                if (l == 0)
                    __hip_atomic_store(&b_g[base_rc + q], nuv[q] / y,
                                       __ATOMIC_RELEASE, __HIP_MEMORY_SCOPE_AGENT);
            }
        }
        batch_barrier(cb + 2 * t + 1);
    }

    // final b^{(50)}
    {
        const float4* bs = reinterpret_cast<const float4*>(b_g + 16 * l);
        #pragma unroll
        for (int m = 0; m < 4; ++m) {
            float4 v4 = bs[m];
            b_r[4*m+0] = v4.x; b_r[4*m+1] = v4.y;
            b_r[4*m+2] = v4.z; b_r[4*m+3] = v4.w;
        }
    }

    // epilogue: pi = a_i K_ij b_j ; cost = sum pi*C ; copy C through
    float* out_pi = out + 4;
    float* out_C  = out + 4 + (size_t)NB * P * P;
    float costp = 0.f;
    #pragma unroll
    for (int q = 0; q < 4; ++q) {
        const int r = base_rc + q;
        const size_t off = (size_t)n * P * P + (size_t)r * P + 16 * l;
        const float4* cs = reinterpret_cast<const float4*>(Cb + (size_t)r * P + 16 * l);
        float4* pd = reinterpret_cast<float4*>(out_pi + off);
        float4* cd = reinterpret_cast<float4*>(out_C + off);
        #pragma unroll
        for (int m = 0; m < 4; ++m) {
            float4 c4 = cs[m];
            float4 p4;
            p4.x = a_own[q] * Kr[q][4*m+0] * b_r[4*m+0];
            p4.y = a_own[q] * Kr[q][4*m+1] * b_r[4*m+1];
            p4.z = a_own[q] * Kr[q][4*m+2] * b_r[4*m+2];
            p4.w = a_own[q] * Kr[q][4*m+3] * b_r[4*m+3];
            costp += p4.x * c4.x + p4.y * c4.y + p4.z * c4.z + p4.w * c4.w;
            pd[m] = p4;
            cd[m] = c4;
        }
    }
    #pragma unroll
    for (int off = 32; off > 0; off >>= 1) costp += __shfl_xor(costp, off, 64);
    __shared__ float reds[4];
    if (l == 0) reds[wq] = costp;
    __syncthreads();
    if (tid == 0) atomicAdd(&out[n], reds[0] + reds[1] + reds[2] + reds[3]);
}

extern "C" void kernel_launch(void* const* d_in, const int* in_sizes, int n_in,
                              void* d_out, int out_size, void* d_ws, size_t ws_size,
                              hipStream_t stream) {
    const float* mu = (const float*)d_in[0];
    const float* nu = (const float*)d_in[1];
    const float* C  = (const float*)d_in[2];
    float* out = (float*)d_out;
    float* wsf = (float*)d_ws;
    int*   cnt = (int*)((char*)d_ws + 2 * NB * P * sizeof(float));  // +32KB

    sink_zero<<<1, 512, 0, stream>>>(cnt, out);
    sink_main<<<NB * WPB, THREADS, 0, stream>>>(mu, nu, C, out, wsf, cnt);
}

// Round 2
// 507.071 us; speedup vs baseline: 7.7421x; 7.7421x over previous
//
#include <hip/hip_runtime.h>

#define NB 4
#define P 1024
#define ITERS 50
#define WPB 64            // workgroups per batch
#define THREADS 256
#define K_COEF (-14.426950408889634f)  // -log2(e)/eps, eps=0.1
#define DELTA 1e-8f

// ws layout: [0,16KB) a_g[NB][P] | [16KB,32KB) b_g[NB][P] | [32KB,+1KB) flags[NB][WPB]

__global__ void sink_zero(int* flags, float* out) {
    int t = threadIdx.x;
    if (t < NB * WPB) flags[t] = 0;
    if (t < NB) out[t] = 0.0f;
}

// Flag barrier: WG w raises flags[w]=tag (relaxed sc1 store); wave 0 polls all
// WPB flags (one coalesced load per lane); one acquire (buffer_inv) per WG so
// subsequent PLAIN vector loads of a_g/b_g refetch past stale L1/L2.
// Data ordering: publishes are relaxed sc1 stores; the compiler-emitted
// s_waitcnt vmcnt(0) before s_barrier (__syncthreads) drains them to the
// coherence point before the flag store issues.
__device__ __forceinline__ void flag_barrier(int* flags, int w, int tag) {
    __syncthreads();   // drains all waves' vmcnt -> publishes globally visible
    const int tid = threadIdx.x;
    if (tid == 0)
        __hip_atomic_store(&flags[w], tag, __ATOMIC_RELAXED, __HIP_MEMORY_SCOPE_AGENT);
    if (tid < WPB) {
        while (__hip_atomic_load(&flags[tid], __ATOMIC_RELAXED, __HIP_MEMORY_SCOPE_AGENT) < tag)
            __builtin_amdgcn_s_sleep(1);
    }
    if (tid == 0)   // one L1/L2 invalidate for the whole WG
        (void)__hip_atomic_load(&flags[w], __ATOMIC_ACQUIRE, __HIP_MEMORY_SCOPE_AGENT);
    __syncthreads();
}

__global__ __launch_bounds__(THREADS, 1)
void sink_main(const float* __restrict__ mu, const float* __restrict__ nu,
               const float* __restrict__ C, float* __restrict__ out,
               float* __restrict__ wsf, int* __restrict__ flags) {
    const int n   = blockIdx.x >> 6;   // batch
    const int w   = blockIdx.x & 63;   // wg within batch
    const int tid = threadIdx.x;
    const int wq  = tid >> 6;          // wave id 0..3
    const int l   = tid & 63;          // lane

    float* a_g = wsf + n * P;
    float* b_g = wsf + NB * P + n * P;
    int*   fb  = flags + n * WPB;

    const float* Cb = C + (size_t)n * P * P;
    const int base_rc = w * 16 + 4 * wq;   // first of this wave's 4 rows (and cols)

    float Kr[4][16], Kt[4][16], muv[4], nuv[4];

    // ---- K rows (coalesced float4): Kr[q][k] = K[base_rc+q][16*l+k]
    #pragma unroll
    for (int q = 0; q < 4; ++q) {
        const int r = base_rc + q;
        const float4* src = reinterpret_cast<const float4*>(Cb + (size_t)r * P + 16 * l);
        #pragma unroll
        for (int m = 0; m < 4; ++m) {
            float4 c4 = src[m];
            Kr[q][4*m+0] = exp2f(K_COEF * c4.x);
            Kr[q][4*m+1] = exp2f(K_COEF * c4.y);
            Kr[q][4*m+2] = exp2f(K_COEF * c4.z);
            Kr[q][4*m+3] = exp2f(K_COEF * c4.w);
        }
        muv[q] = mu[n * P + r] + DELTA;
        nuv[q] = nu[n * P + r] + DELTA;
    }
    // ---- K columns: wave's 4 cols are contiguous -> float4 per row
    //      Kt[q][k] = K[16*l+k][base_rc+q]
    #pragma unroll
    for (int k = 0; k < 16; ++k) {
        const float4 c4 = *reinterpret_cast<const float4*>(
            Cb + (size_t)(16 * l + k) * P + base_rc);
        Kt[0][k] = exp2f(K_COEF * c4.x);
        Kt[1][k] = exp2f(K_COEF * c4.y);
        Kt[2][k] = exp2f(K_COEF * c4.z);
        Kt[3][k] = exp2f(K_COEF * c4.w);
    }

    float b_r[16];
    #pragma unroll
    for (int k = 0; k < 16; ++k) b_r[k] = 1.0f;   // v=0 -> b=1
    float a_own[4];

    for (int t = 0; t < ITERS; ++t) {
        if (t) {
            const float4* bs = reinterpret_cast<const float4*>(b_g + 16 * l);
            #pragma unroll
            for (int m = 0; m < 4; ++m) {
                float4 v4 = bs[m];
                b_r[4*m+0] = v4.x; b_r[4*m+1] = v4.y;
                b_r[4*m+2] = v4.z; b_r[4*m+3] = v4.w;
            }
        }
        // phase A: a_i = (mu_i+d) / sum_j K_ij b_j
        #pragma unroll
        for (int q = 0; q < 4; ++q) {
            float y = 0.f;
            #pragma unroll
            for (int k = 0; k < 16; ++k) y += Kr[q][k] * b_r[k];
            #pragma unroll
            for (int off = 32; off > 0; off >>= 1) y += __shfl_xor(y, off, 64);
            a_own[q] = muv[q] / y;
            if (l == 0)
                __hip_atomic_store(&a_g[base_rc + q], a_own[q],
                                   __ATOMIC_RELAXED, __HIP_MEMORY_SCOPE_AGENT);
        }
        flag_barrier(fb, w, 2 * t + 1);
        // phase B: b_j = (nu_j+d) / sum_i K_ij a_i
        {
            float a_r[16];
            const float4* as = reinterpret_cast<const float4*>(a_g + 16 * l);
            #pragma unroll
            for (int m = 0; m < 4; ++m) {
                float4 v4 = as[m];
                a_r[4*m+0] = v4.x; a_r[4*m+1] = v4.y;
                a_r[4*m+2] = v4.z; a_r[4*m+3] = v4.w;
            }
            #pragma unroll
            for (int q = 0; q < 4; ++q) {
                float y = 0.f;
                #pragma unroll
                for (int k = 0; k < 16; ++k) y += Kt[q][k] * a_r[k];
                #pragma unroll
                for (int off = 32; off > 0; off >>= 1) y += __shfl_xor(y, off, 64);
                if (l == 0)
                    __hip_atomic_store(&b_g[base_rc + q], nuv[q] / y,
                                       __ATOMIC_RELAXED, __HIP_MEMORY_SCOPE_AGENT);
            }
        }
        flag_barrier(fb, w, 2 * t + 2);
    }

    // final b^{(50)}
    {
        const float4* bs = reinterpret_cast<const float4*>(b_g + 16 * l);
        #pragma unroll
        for (int m = 0; m < 4; ++m) {
            float4 v4 = bs[m];
            b_r[4*m+0] = v4.x; b_r[4*m+1] = v4.y;
            b_r[4*m+2] = v4.z; b_r[4*m+3] = v4.w;
        }
    }

    // epilogue: pi = a_i K_ij b_j ; cost = sum pi*C ; copy C through
    float* out_pi = out + 4;
    float* out_C  = out + 4 + (size_t)NB * P * P;
    float costp = 0.f;
    #pragma unroll
    for (int q = 0; q < 4; ++q) {
        const int r = base_rc + q;
        const size_t off = (size_t)n * P * P + (size_t)r * P + 16 * l;
        const float4* cs = reinterpret_cast<const float4*>(Cb + (size_t)r * P + 16 * l);
        float4* pd = reinterpret_cast<float4*>(out_pi + off);
        float4* cd = reinterpret_cast<float4*>(out_C + off);
        #pragma unroll
        for (int m = 0; m < 4; ++m) {
            float4 c4 = cs[m];
            float4 p4;
            p4.x = a_own[q] * Kr[q][4*m+0] * b_r[4*m+0];
            p4.y = a_own[q] * Kr[q][4*m+1] * b_r[4*m+1];
            p4.z = a_own[q] * Kr[q][4*m+2] * b_r[4*m+2];
            p4.w = a_own[q] * Kr[q][4*m+3] * b_r[4*m+3];
            costp += p4.x * c4.x + p4.y * c4.y + p4.z * c4.z + p4.w * c4.w;
            pd[m] = p4;
            cd[m] = c4;
        }
    }
    #pragma unroll
    for (int off = 32; off > 0; off >>= 1) costp += __shfl_xor(costp, off, 64);
    __shared__ float reds[4];
    if (l == 0) reds[wq] = costp;
    __syncthreads();
    if (tid == 0) atomicAdd(&out[n], reds[0] + reds[1] + reds[2] + reds[3]);
}

extern "C" void kernel_launch(void* const* d_in, const int* in_sizes, int n_in,
                              void* d_out, int out_size, void* d_ws, size_t ws_size,
                              hipStream_t stream) {
    const float* mu = (const float*)d_in[0];
    const float* nu = (const float*)d_in[1];
    const float* C  = (const float*)d_in[2];
    float* out = (float*)d_out;
    float* wsf = (float*)d_ws;
    int*   flags = (int*)((char*)d_ws + 2 * NB * P * sizeof(float));  // +32KB

    sink_zero<<<1, 512, 0, stream>>>(flags, out);
    sink_main<<<NB * WPB, THREADS, 0, stream>>>(mu, nu, C, out, wsf, flags);
}